// Round 9
// baseline (110.633 us; speedup 1.0000x reference)
//
#include <hip/hip_runtime.h>

// Problem constants (from reference init_kwargs)
#define BB   64
#define KP   21
#define HH   256
#define KS   9
#define PADK 4   // KS/2

#define NPLANES       (BB * KP)                    // 1344
#define F4_PER_PLANE  (HH * HH / 4)                // 16384
#define NBLOCKS       256                          // 1 block/CU (~rocclr fill occupancy)
#define THREADS       256
#define NTH_TOTAL     (NBLOCKS * THREADS)          // 65536 float4 / sweep (1 MB window)
#define F4_TOTAL      (NPLANES * F4_PER_PLANE)     // 22,020,096
#define NSWEEP        (F4_TOTAL / NTH_TOTAL)       // 336

typedef float vfloat4 __attribute__((ext_vector_type(4)));

// Fused zero+patch cloning the rocclr fill shape: LOW occupancy (4 waves/CU),
// tiny register footprint, grid-stride with a 1 MB device-wide window.
// Ownership under this addressing: float4 g4 is owned by block (g4>>8)&255;
// owner(plane p, row i) = (64p + (i>>2)) & 255, so block b owns planes
// p ≡ (b>>6) (mod 4) at rows [4*(b&63), 4*(b&63)+4).
// Phase 2 after __syncthreads (vmcnt(0) drained per wave before s_barrier —
// ordering mechanism proven correct rounds 5-8).
__global__ __launch_bounds__(THREADS)
void heatmap_lowocc_kernel(const int* __restrict__ x,
                           const float* __restrict__ k2d,
                           vfloat4* __restrict__ out) {
    const int t = threadIdx.x;
    const int b = blockIdx.x;

    // ---- phase 1: low-concurrency grid-stride zero stream ----
    vfloat4* ptr = out + (b * THREADS + t);
#pragma unroll 8
    for (int it = 0; it < NSWEEP; ++it) {
        *ptr = (vfloat4)0.0f;          // wave: 1 KiB contiguous per store
        ptr += NTH_TOTAL;              // next 1 MB window
    }

    __syncthreads();

    // ---- phase 2: patch overwrite for addresses this block owns ----
    if (t < KS * KS) {
        const int dy = t / KS;         // 0..8
        const int dx = t - dy * KS;
        const int pr = b >> 6;         // plane residue (mod 4)
        const int m  = b & 63;         // owned row window [4m, 4m+4)
        const float wt = 10.0f * k2d[(KS - 1 - dy) * KS + (KS - 1 - dx)];
        float* of = (float*)out;
        for (int q = 0; q < NPLANES / 4; ++q) {    // 336 candidate planes
            const int p = pr + (q << 2);
            const int r = x[2 * p];
            const int c = x[2 * p + 1];
            const int i = r - PADK + dy;
            const int j = c - PADK + dx;
            // (i>>2)==m implies i in [4m,4m+4) subset [0,256); i<0 gives -1 != m
            if ((i >> 2) == m && j >= 0 && j < HH)
                of[(size_t)p * (HH * HH) + i * HH + j] = wt;
        }
    }
}

extern "C" void kernel_launch(void* const* d_in, const int* in_sizes, int n_in,
                              void* d_out, int out_size, void* d_ws, size_t ws_size,
                              hipStream_t stream) {
    const int*   x   = (const int*)d_in[0];    // [B, KP, 2] int32
    const float* k2d = (const float*)d_in[1];  // [KS, KS] float32
    vfloat4*     out = (vfloat4*)d_out;        // [B, KP, H, H] float32

    heatmap_lowocc_kernel<<<NBLOCKS, THREADS, 0, stream>>>(x, k2d, out);
}